// Round 3
// baseline (858.616 us; speedup 1.0000x reference)
//
#include <hip/hip_runtime.h>

// GCNEncoder round 19: CSR-free aggregation.
// The dst>>7 bucket partition already gives 128-node locality, so each gather
// block keeps its bucket's whole output tile in LDS (128 x 64 f32, stride-65
// padded) and streams the bucket's part[] segment in arrival order:
// coalesced uint4 record reads + random 128B T-row read + LDS f32 atomics.
// Deletes the entire CSR build (count/scan/scatter), rec[] and rs[]:
// pipeline = memset, p2, dis||gemm1, gatherB x2, gemm2_pool, divide.
constexpr int N_NODES  = 50000;
constexpr int N_EDGES  = 800000;
constexpr int N_GRAPHS = 256;
constexpr int IN_DIM   = 128;
constexpr int HID      = 64;
constexpr int EMB      = 128;
constexpr int NBKT     = 391;                       // buckets: dst>>7 (128 nodes)
constexpr int BCAP     = 4096;                      // slots/bucket (mean 2048, sigma~45)
constexpr int EB       = (N_EDGES + 1023) / 1024;   // 782 edge blocks
constexpr int GB       = (N_NODES + 31) / 32;       // 1563 gemm1 blocks (32 nodes)
constexpr int GSB      = (N_NODES + 255) / 256;     // 196 gstart blocks
constexpr int NB2      = 64;                        // nodes per gemm2_pool block

// Workspace layout in 4-byte units (ws is 268 MB).
constexpr size_t OFF_POOL = 0;                                   // f32 [256*128]
constexpr size_t OFF_GCUR = 32768;                               // i32 [391] (memset w/ pool)
constexpr size_t OFF_GST  = 33160;                               // i32 [257]
constexpr size_t OFF_DIS  = 33424;                               // f32 [50000]
constexpr size_t OFF_PART = 83424;                               // uint4 [391*4096] (16B-aligned)
constexpr size_t OFF_H1   = OFF_PART + 4 * (size_t)NBKT * BCAP;  // bf16x2 [50000*32]
constexpr size_t OFF_H1P  = OFF_H1 + 2 * (size_t)N_NODES * 16;   // bf16x2 [50000*32]
constexpr size_t OFF_AGG2 = OFF_H1P;    // f32 [50000*64]; overlays h1p (dead after gather1)

// bf16 helpers: pack with round-to-nearest-even; unpack via shift.
__device__ inline unsigned bf16r(float f) {
    unsigned u = __float_as_uint(f);
    return (u + 0x7fffu + ((u >> 16) & 1u)) >> 16;
}
__device__ inline unsigned bf16pack2(float lo, float hi) {
    return bf16r(lo) | (bf16r(hi) << 16);
}
__device__ inline float bflo(unsigned v) { return __uint_as_float(v << 16); }
__device__ inline float bfhi(unsigned v) { return __uint_as_float(v & 0xffff0000u); }

__device__ inline void fma4(float4& acc, float s, const float4& v) {
    acc.x += s * v.x; acc.y += s * v.y; acc.z += s * v.z; acc.w += s * v.w;
}

// ---- P2: edges -> fixed-capacity bucket segments (global atomic claims) ----
// blocks [0,EB): 1024 edges each, LDS hist -> 1 atomicAdd/bucket -> scatter.
// blocks [EB,EB+GSB): sorted-batch boundary detection (gstart).
__global__ __launch_bounds__(256) void k_p2(const int* __restrict__ src,
                                            const int* __restrict__ dst,
                                            const float* __restrict__ ew,
                                            int* __restrict__ gcur,
                                            uint4* __restrict__ part,
                                            const int* __restrict__ batch,
                                            int* __restrict__ gstart) {
    __shared__ int   lb[NBKT];
    __shared__ int   lc[NBKT];
    __shared__ int   es[1024];
    __shared__ int   ed[1024];
    __shared__ float ee[1024];
    int tid = threadIdx.x;
    if (blockIdx.x >= EB) {
        // ---- gstart role ----
        int i = (blockIdx.x - EB) * 256 + tid;
        if (i >= N_NODES) return;
        int g = batch[i];
        if (i == 0) {
            for (int gg = 0; gg <= g; ++gg) gstart[gg] = 0;
        } else {
            int gp = batch[i - 1];
            for (int gg = gp + 1; gg <= g; ++gg) gstart[gg] = i;
        }
        if (i == N_NODES - 1) {
            for (int gg = g + 1; gg <= N_GRAPHS; ++gg) gstart[gg] = N_NODES;
        }
        return;
    }
    for (int i = tid; i < NBKT; i += 256) lc[i] = 0;
    __syncthreads();
    int base = blockIdx.x * 1024;
    #pragma unroll
    for (int j = 0; j < 4; ++j) {
        int idx = j * 256 + tid;
        int e = base + idx;
        int d = 0, s = 0; float w = 0.f;
        if (e < N_EDGES) {
            d = dst[e]; s = src[e]; w = ew[e];
            atomicAdd(&lc[d >> 7], 1);
        }
        es[idx] = s; ed[idx] = d; ee[idx] = w;
    }
    __syncthreads();
    for (int i = tid; i < NBKT; i += 256) {
        int c = lc[i];
        lb[i] = c ? (i * BCAP + atomicAdd(&gcur[i], c)) : 0;
        lc[i] = 0;
    }
    __syncthreads();
    #pragma unroll
    for (int j = 0; j < 4; ++j) {
        int idx = j * 256 + tid;
        int e = base + idx;
        if (e < N_EDGES) {
            int d = ed[idx];
            int b = d >> 7;
            int r = atomicAdd(&lc[b], 1);
            part[lb[b] + r] = make_uint4((unsigned)es[idx], (unsigned)d,
                                         __float_as_uint(ee[idx]), 0u);
        }
    }
}

// ---- DIS (+gemm1 het-fused): per-bucket degree-weight sums + dis ----
// blocks [0,NBKT): bucket b: dgw via LDS atomics, dis = rsqrt(dgw+1).
// blocks [NBKT,NBKT+GB): h1p(bf16) = x @ W1 (32 nodes/block).
constexpr int SMEM_BYTES = 32768 + 32 * (IN_DIM + 4) * 4;   // 49664 B
__global__ __launch_bounds__(256) void k_dis_gemm1(const uint4* __restrict__ part,
                                                   const int* __restrict__ gcur,
                                                   float* __restrict__ dis,
                                                   const float* __restrict__ x,
                                                   const float* __restrict__ W1,
                                                   unsigned* __restrict__ h) {
    __shared__ alignas(16) unsigned char smem[SMEM_BYTES];
    int tid = threadIdx.x;
    if (blockIdx.x < NBKT) {
        float* dgw = (float*)smem;                  // 128 f32
        if (tid < 128) dgw[tid] = 0.f;
        __syncthreads();
        int b = blockIdx.x;
        int ebeg = b * BCAP;
        int ne = gcur[b]; if (ne > BCAP) ne = BCAP;
        for (int i = tid; i < ne; i += 256) {
            uint4 r = part[ebeg + i];
            atomicAdd(&dgw[(int)r.y & 127], __uint_as_float(r.z));
        }
        __syncthreads();
        if (tid < 128) {
            int node = (b << 7) + tid;
            if (node < N_NODES) dis[node] = rsqrtf(dgw[tid] + 1.0f);
        }
        return;
    }
    // ---- gemm1 role: 32 nodes/block, thread = 2 nodes x 4 cols ----
    float* Ws = (float*)smem;                                         // 32 KB
    float (*xs)[IN_DIM + 4] = (float (*)[IN_DIM + 4])(smem + 32768);  // 16.9 KB
    int bid = blockIdx.x - NBKT;
    const float4* W4 = (const float4*)W1;
    float4* Ws4 = (float4*)Ws;
    for (int i = tid; i < IN_DIM * HID / 4; i += 256) Ws4[i] = W4[i];
    int base = bid * 32;
    const float4* X4 = (const float4*)x;
    for (int i = tid; i < 32 * 32; i += 256) {           // 32 rows x 32 float4
        int ln = i >> 5, kq = i & 31;
        int node = base + ln;
        float4 v = (node < N_NODES) ? X4[(size_t)node * 32 + kq]
                                    : make_float4(0.f, 0.f, 0.f, 0.f);
        *(float4*)&xs[ln][kq * 4] = v;
    }
    __syncthreads();
    int np = tid >> 4;            // node pair 0..15
    int q  = tid & 15;            // col quad 0..15
    int n0 = np * 2, n1 = n0 + 1;
    float4 a0 = make_float4(0.f, 0.f, 0.f, 0.f);
    float4 a1 = a0;
    #pragma unroll 4
    for (int k4 = 0; k4 < IN_DIM; k4 += 4) {
        float4 xv0 = *(const float4*)&xs[n0][k4];
        float4 xv1 = *(const float4*)&xs[n1][k4];
        float4 w0 = Ws4[(k4 + 0) * 16 + q];
        float4 w1 = Ws4[(k4 + 1) * 16 + q];
        float4 w2 = Ws4[(k4 + 2) * 16 + q];
        float4 w3 = Ws4[(k4 + 3) * 16 + q];
        fma4(a0, xv0.x, w0); fma4(a0, xv0.y, w1); fma4(a0, xv0.z, w2); fma4(a0, xv0.w, w3);
        fma4(a1, xv1.x, w0); fma4(a1, xv1.y, w1); fma4(a1, xv1.z, w2); fma4(a1, xv1.w, w3);
    }
    int nd0 = base + n0, nd1 = base + n1;
    if (nd0 < N_NODES) {
        uint2 p = make_uint2(bf16pack2(a0.x, a0.y), bf16pack2(a0.z, a0.w));
        ((uint2*)h)[(size_t)nd0 * 16 + q] = p;
    }
    if (nd1 < N_NODES) {
        uint2 p = make_uint2(bf16pack2(a1.x, a1.y), bf16pack2(a1.z, a1.w));
        ((uint2*)h)[(size_t)nd1 * 16 + q] = p;
    }
}

// ---- CSR-free bucket gather: LDS output tile + streamed edge segment ----
// One block per bucket (128 nodes). acc[128][65] f32 (stride 65 -> ~2-way
// bank aliasing). Edge loop: 16 edges/iter, 16 lanes/edge (4 dims each).
// Epilogue adds self-loop, scales by dis[n], bias+relu (pass1) and stores.
// out[n] = dis[n]*(sum_e dis[src]*ew*T[src] + dis[n]*T[n]) (+bias,relu)
template <bool PASS1>
__global__ __launch_bounds__(256) void k_gatherB(const uint4* __restrict__ part,
                                                 const int* __restrict__ gcur,
                                                 const float* __restrict__ dis,
                                                 const unsigned* __restrict__ T,
                                                 const float* __restrict__ bias,
                                                 void* __restrict__ outv) {
    __shared__ float acc[128][65];          // 33.3 KB
    int tid = threadIdx.x;
    for (int i = tid; i < 128 * 65; i += 256) ((float*)acc)[i] = 0.f;
    __syncthreads();
    int b = blockIdx.x;
    int ebeg = b * BCAP;
    int ne = gcur[b]; if (ne > BCAP) ne = BCAP;
    int l  = tid & 15;            // dim quad 0..15
    int eg = tid >> 4;            // edge subgroup 0..15
    const uint2* T2 = (const uint2*)T;
    for (int i0 = 0; i0 < ne; i0 += 16) {
        int e = i0 + eg;
        if (e < ne) {
            uint4 r = part[ebeg + e];
            unsigned s = r.x;
            int ld = (int)r.y & 127;
            float w = dis[s] * __uint_as_float(r.z);
            uint2 t = T2[(size_t)s * 16 + l];
            float* a = &acc[ld][4 * l];
            atomicAdd(a + 0, bflo(t.x) * w);
            atomicAdd(a + 1, bfhi(t.x) * w);
            atomicAdd(a + 2, bflo(t.y) * w);
            atomicAdd(a + 3, bfhi(t.y) * w);
        }
    }
    __syncthreads();
    // ---- epilogue: 128 nodes x 16 quads ----
    int base_node = b << 7;
    for (int it = tid; it < 128 * 16; it += 256) {
        int ln = it >> 4, q = it & 15;
        int n = base_node + ln;
        if (n >= N_NODES) continue;
        float di = dis[n];
        uint2 t = T2[(size_t)n * 16 + q];   // self-loop row
        float a0 = acc[ln][4 * q + 0] + bflo(t.x) * di;
        float a1 = acc[ln][4 * q + 1] + bfhi(t.x) * di;
        float a2 = acc[ln][4 * q + 2] + bflo(t.y) * di;
        float a3 = acc[ln][4 * q + 3] + bfhi(t.y) * di;
        a0 *= di; a1 *= di; a2 *= di; a3 *= di;
        if (PASS1) {
            float4 bq = ((const float4*)bias)[q];
            a0 = fmaxf(a0 + bq.x, 0.f);
            a1 = fmaxf(a1 + bq.y, 0.f);
            a2 = fmaxf(a2 + bq.z, 0.f);
            a3 = fmaxf(a3 + bq.w, 0.f);
            ((uint2*)outv)[(size_t)n * 16 + q] =
                make_uint2(bf16pack2(a0, a1), bf16pack2(a2, a3));
        } else {
            ((float4*)outv)[(size_t)n * 16 + q] = make_float4(a0, a1, a2, a3);
        }
    }
}

// ---- fused: h2 = relu(agg2 @ W2 + b2); pool[batch] += h2 (run-length) ----
__global__ __launch_bounds__(256) void k_gemm2_pool(const float* __restrict__ agg,
                                                    const float* __restrict__ W2,
                                                    const float* __restrict__ b2,
                                                    const int* __restrict__ batch,
                                                    float* __restrict__ pool) {
    __shared__ float Ws[HID * EMB];         // 32 KB
    __shared__ float as[NB2][HID];          // 16 KB (broadcast reads)
    __shared__ int   bs[NB2];
    int tid = threadIdx.x;
    const float4* W4 = (const float4*)W2;
    float4* Ws4 = (float4*)Ws;
    for (int i = tid; i < HID * EMB / 4; i += 256) Ws4[i] = W4[i];
    int base = blockIdx.x * NB2;
    const float4* A4 = (const float4*)agg;
    float4* as4 = (float4*)as;
    for (int i = tid; i < NB2 * HID / 4; i += 256) {
        int node = base + (i >> 4);
        as4[i] = (node < N_NODES) ? A4[(size_t)node * 16 + (i & 15)]
                                  : make_float4(0.f, 0.f, 0.f, 0.f);
    }
    if (tid < NB2) {
        int node = base + tid;
        bs[tid] = (node < N_NODES) ? batch[node] : -1;
    }
    __syncthreads();

    int c = tid & 31;             // column-quad id (4 cols)
    int s = tid >> 5;             // node slice 0..7 (8 contiguous nodes)
    int jc = c * 4;
    int nb = s * 8;
    float4 acc[8];
    #pragma unroll
    for (int i = 0; i < 8; ++i) acc[i] = make_float4(0.f, 0.f, 0.f, 0.f);
    #pragma unroll 4
    for (int k4 = 0; k4 < HID; k4 += 4) {
        float4 w0 = Ws4[(k4 + 0) * 32 + c];
        float4 w1 = Ws4[(k4 + 1) * 32 + c];
        float4 w2 = Ws4[(k4 + 2) * 32 + c];
        float4 w3 = Ws4[(k4 + 3) * 32 + c];
        #pragma unroll
        for (int i = 0; i < 8; ++i) {
            float4 av = *(const float4*)&as[nb + i][k4];
            fma4(acc[i], av.x, w0); fma4(acc[i], av.y, w1);
            fma4(acc[i], av.z, w2); fma4(acc[i], av.w, w3);
        }
    }
    // Epilogue: bias + relu + run-length pooled accumulate (batch sorted).
    float4 bq = *(const float4*)&b2[jc];
    float4 racc = make_float4(0.f, 0.f, 0.f, 0.f);
    int gcur = -1;
    #pragma unroll
    for (int i = 0; i < 8; ++i) {
        int g = bs[nb + i];
        if (g != gcur) {
            if (gcur >= 0) {
                float* p = &pool[(size_t)gcur * EMB + jc];
                atomicAdd(p + 0, racc.x); atomicAdd(p + 1, racc.y);
                atomicAdd(p + 2, racc.z); atomicAdd(p + 3, racc.w);
            }
            racc = make_float4(0.f, 0.f, 0.f, 0.f);
            gcur = g;
        }
        if (g < 0) continue;
        racc.x += fmaxf(acc[i].x + bq.x, 0.f);
        racc.y += fmaxf(acc[i].y + bq.y, 0.f);
        racc.z += fmaxf(acc[i].z + bq.z, 0.f);
        racc.w += fmaxf(acc[i].w + bq.w, 0.f);
    }
    if (gcur >= 0) {
        float* p = &pool[(size_t)gcur * EMB + jc];
        atomicAdd(p + 0, racc.x); atomicAdd(p + 1, racc.y);
        atomicAdd(p + 2, racc.z); atomicAdd(p + 3, racc.w);
    }
}

__global__ void k_divide(const float* __restrict__ pool, const int* __restrict__ gstart,
                         float* __restrict__ out) {
    int idx = blockIdx.x * blockDim.x + threadIdx.x;
    if (idx >= N_GRAPHS * EMB) return;
    int g = idx >> 7;
    float c = (float)(gstart[g + 1] - gstart[g]);
    out[idx] = pool[idx] / fmaxf(c, 1.0f);
}

extern "C" void kernel_launch(void* const* d_in, const int* in_sizes, int n_in,
                              void* d_out, int out_size, void* d_ws, size_t ws_size,
                              hipStream_t stream) {
    const float* x     = (const float*)d_in[0];
    const int*   eidx  = (const int*)d_in[1];     // [2, E]: src then dst
    const float* ew    = (const float*)d_in[2];
    const int*   batch = (const int*)d_in[3];
    const float* W1    = (const float*)d_in[4];
    const float* b1    = (const float*)d_in[5];
    const float* W2    = (const float*)d_in[6];
    const float* b2    = (const float*)d_in[7];
    float* out = (float*)d_out;

    const int* src = eidx;
    const int* dst = eidx + N_EDGES;

    float* ws     = (float*)d_ws;
    float* pool   = ws + OFF_POOL;
    int*   gcur   = (int*)(ws + OFF_GCUR);
    int*   gstart = (int*)(ws + OFF_GST);
    float* dis    = ws + OFF_DIS;
    uint4* part   = (uint4*)(ws + OFF_PART);
    unsigned* h1  = (unsigned*)(ws + OFF_H1);   // bf16x2
    unsigned* h1p = (unsigned*)(ws + OFF_H1P);  // bf16x2
    float* agg2   = ws + OFF_AGG2;              // f32; overlays h1p (dead after gather1)

    // Zero pool + bucket cursors in one memset (they are adjacent).
    (void)hipMemsetAsync(pool, 0, (size_t)(32768 + NBKT) * sizeof(float), stream);

    // Edges -> bucket segments (atomic range claims) + gstart detection.
    k_p2<<<EB + GSB, 256, 0, stream>>>(src, dst, ew, gcur, part, batch, gstart);

    // Per-bucket degree/dis, het-fused with layer-1 linear.
    k_dis_gemm1<<<NBKT + GB, 256, 0, stream>>>(part, gcur, dis, x, W1, h1p);

    // Layer 1 aggregate + bias + relu: bucket-LDS accumulate, bf16 out.
    k_gatherB<true><<<NBKT, 256, 0, stream>>>(part, gcur, dis, h1p, b1, h1);

    // Layer 2 aggregate BEFORE the linear: bf16 h1 -> f32 agg2.
    k_gatherB<false><<<NBKT, 256, 0, stream>>>(part, gcur, dis, h1, nullptr, agg2);

    // Fused layer-2 linear + relu + run-length pooled accumulate.
    k_gemm2_pool<<<(N_NODES + NB2 - 1) / NB2, 256, 0, stream>>>(agg2, W2, b2, batch, pool);

    k_divide<<<(N_GRAPHS * EMB + 255) / 256, 256, 0, stream>>>(pool, gstart, out);
}

// Round 4
// 224.612 us; speedup vs baseline: 3.8227x; 3.8227x over previous
//
#include <hip/hip_runtime.h>

// GCNEncoder round 20: r17's proven-fast CSR gather + r18's single-kernel
// atomic-segment partition. The 4-kernel counting-sort chain (p1/btot/kab/kc)
// is gone (k_p2 claims fixed-capacity 4096-slot bucket segments with one
// LDS-aggregated global atomicAdd per block,bucket); the gather is r17's
// verbatim (no pair padding, no premultiply writeback - both measured as
// regressions in r18), with begin() adapted to the segmented rec layout.
// Pipeline: memset, p2(+gstart), p3||gemm1, gather x2, gemm2_pool, divide.
constexpr int N_NODES  = 50000;
constexpr int N_EDGES  = 800000;
constexpr int N_GRAPHS = 256;
constexpr int IN_DIM   = 128;
constexpr int HID      = 64;
constexpr int EMB      = 128;
constexpr int NBKT     = 391;                       // buckets: dst>>7 (128 nodes)
constexpr int BCAP     = 4096;                      // slots/bucket (mean 2048, sigma~45)
constexpr int EB       = (N_EDGES + 1023) / 1024;   // 782 edge blocks
constexpr int GB       = (N_NODES + 31) / 32;       // 1563 gemm1 blocks (32 nodes)
constexpr int GSB      = (N_NODES + 255) / 256;     // 196 gstart blocks
constexpr int NB2      = 64;                        // nodes per gemm2_pool block

// Workspace layout in 4-byte units (ws is 268 MB).
constexpr size_t OFF_POOL = 0;                                   // f32 [256*128]
constexpr size_t OFF_GCUR = 32768;                               // i32 [391] (memset w/ pool)
constexpr size_t OFF_GST  = 33160;                               // i32 [257]
constexpr size_t OFF_DIS  = 33424;                               // f32 [50000]
constexpr size_t OFF_RS   = 83424;                               // i32 [50000]
constexpr size_t OFF_REC  = 133424;                              // uint2 [391*4096] (16B-aligned)
constexpr size_t OFF_PART = OFF_REC + 2 * (size_t)NBKT * BCAP;   // uint4 [391*4096] (16B-aligned)
constexpr size_t OFF_H1   = OFF_PART;   // bf16x2 [50000*32]; overlays part (dead after P3)
constexpr size_t OFF_H1P  = OFF_PART + 4 * (size_t)NBKT * BCAP;  // bf16x2 [50000*32]
constexpr size_t OFF_AGG2 = OFF_H1P;    // f32 [50000*64]; overlays h1p (dead after gather1)

// bf16 helpers: pack with round-to-nearest-even; unpack via shift.
__device__ inline unsigned bf16r(float f) {
    unsigned u = __float_as_uint(f);
    return (u + 0x7fffu + ((u >> 16) & 1u)) >> 16;
}
__device__ inline unsigned bf16pack2(float lo, float hi) {
    return bf16r(lo) | (bf16r(hi) << 16);
}
__device__ inline float bflo(unsigned v) { return __uint_as_float(v << 16); }
__device__ inline float bfhi(unsigned v) { return __uint_as_float(v & 0xffff0000u); }

__device__ inline void fma4(float4& acc, float s, const float4& v) {
    acc.x += s * v.x; acc.y += s * v.y; acc.z += s * v.z; acc.w += s * v.w;
}

// ---- P2: edges -> fixed-capacity bucket segments (global atomic claims) ----
// blocks [0,EB): 1024 edges each, LDS hist -> 1 atomicAdd/bucket -> scatter.
// blocks [EB,EB+GSB): sorted-batch boundary detection (gstart).
__global__ __launch_bounds__(256) void k_p2(const int* __restrict__ src,
                                            const int* __restrict__ dst,
                                            const float* __restrict__ ew,
                                            int* __restrict__ gcur,
                                            uint4* __restrict__ part,
                                            const int* __restrict__ batch,
                                            int* __restrict__ gstart) {
    __shared__ int   lb[NBKT];
    __shared__ int   lc[NBKT];
    __shared__ int   es[1024];
    __shared__ int   ed[1024];
    __shared__ float ee[1024];
    int tid = threadIdx.x;
    if (blockIdx.x >= EB) {
        // ---- gstart role ----
        int i = (blockIdx.x - EB) * 256 + tid;
        if (i >= N_NODES) return;
        int g = batch[i];
        if (i == 0) {
            for (int gg = 0; gg <= g; ++gg) gstart[gg] = 0;
        } else {
            int gp = batch[i - 1];
            for (int gg = gp + 1; gg <= g; ++gg) gstart[gg] = i;
        }
        if (i == N_NODES - 1) {
            for (int gg = g + 1; gg <= N_GRAPHS; ++gg) gstart[gg] = N_NODES;
        }
        return;
    }
    for (int i = tid; i < NBKT; i += 256) lc[i] = 0;
    __syncthreads();
    int base = blockIdx.x * 1024;
    #pragma unroll
    for (int j = 0; j < 4; ++j) {
        int idx = j * 256 + tid;
        int e = base + idx;
        int d = 0, s = 0; float w = 0.f;
        if (e < N_EDGES) {
            d = dst[e]; s = src[e]; w = ew[e];
            atomicAdd(&lc[d >> 7], 1);
        }
        es[idx] = s; ed[idx] = d; ee[idx] = w;
    }
    __syncthreads();
    for (int i = tid; i < NBKT; i += 256) {
        int c = lc[i];
        lb[i] = c ? (i * BCAP + atomicAdd(&gcur[i], c)) : 0;
        lc[i] = 0;
    }
    __syncthreads();
    #pragma unroll
    for (int j = 0; j < 4; ++j) {
        int idx = j * 256 + tid;
        int e = base + idx;
        if (e < N_EDGES) {
            int d = ed[idx];
            int b = d >> 7;
            int r = atomicAdd(&lc[b], 1);
            part[lb[b] + r] = make_uint4((unsigned)es[idx], (unsigned)d,
                                         __float_as_uint(ee[idx]), 0u);
        }
    }
}

// ---- P3 (+gemm1 het-fused): per-bucket CSR finalize + degree + dis ----
// blocks [0,NBKT): bucket b = 128 contiguous nodes, records cached in LDS.
// blocks [NBKT,NBKT+GB): h1p(bf16) = x @ W1 (32 nodes/block).
constexpr int SMEM_BYTES = 32768 + 32 * (IN_DIM + 4) * 4;   // 49664 B
__global__ __launch_bounds__(256) void k_p3_gemm1(const uint4* __restrict__ part,
                                                  const int* __restrict__ gcur,
                                                  int* __restrict__ rs,
                                                  float* __restrict__ dis,
                                                  uint2* __restrict__ rec,
                                                  const float* __restrict__ x,
                                                  const float* __restrict__ W1,
                                                  unsigned* __restrict__ h) {
    __shared__ alignas(16) unsigned char smem[SMEM_BYTES];
    int tid = threadIdx.x;
    if (blockIdx.x < NBKT) {
        uint2* cache = (uint2*)smem;                    // 4096 recs = 32 KB
        int*   cnt   = (int*)(smem + 32768);
        float* dgw   = (float*)(smem + 32768 + 512);
        int*   scn   = (int*)(smem + 32768 + 1024);
        int*   curx  = (int*)(smem + 32768 + 1536);
        int b = blockIdx.x;
        int ebeg = b * BCAP;
        int ne = gcur[b]; if (ne > BCAP) ne = BCAP;
        if (tid < 128) { cnt[tid] = 0; dgw[tid] = 0.f; }
        __syncthreads();
        for (int i = tid; i < ne; i += 256) {
            uint4 r = part[ebeg + i];
            int ld = (int)r.y & 127;
            cache[i] = make_uint2(r.x | ((unsigned)ld << 16), r.z);  // src<2^16
            atomicAdd(&cnt[ld], 1);
            atomicAdd(&dgw[ld], __uint_as_float(r.z));
        }
        __syncthreads();
        int c = (tid < 128) ? cnt[tid] : 0;
        if (tid < 128) scn[tid] = c;
        __syncthreads();
        for (int off = 1; off < 128; off <<= 1) {
            int a = (tid >= off && tid < 128) ? scn[tid - off] : 0;
            __syncthreads();
            if (tid < 128) scn[tid] += a;
            __syncthreads();
        }
        if (tid < 128) {
            int node = (b << 7) + tid;
            if (node < N_NODES) {
                rs[node] = ebeg + scn[tid];             // end pointer
                dis[node] = rsqrtf(dgw[tid] + 1.0f);    // + self-loop weight 1
            }
            curx[tid] = ebeg + scn[tid] - c;            // row start cursor
        }
        __syncthreads();
        for (int i = tid; i < ne; i += 256) {
            uint2 q = cache[i];
            int ld = (int)(q.x >> 16);                  // src<2^16 -> top = ld
            int pos = atomicAdd(&curx[ld], 1);
            rec[pos] = make_uint2(q.x & 0xFFFFu, q.y);  // (src, ew_bits)
        }
        return;
    }
    // ---- gemm1 role: 32 nodes/block, thread = 2 nodes x 4 cols ----
    float* Ws = (float*)smem;                                         // 32 KB
    float (*xs)[IN_DIM + 4] = (float (*)[IN_DIM + 4])(smem + 32768);  // 16.9 KB
    int bid = blockIdx.x - NBKT;
    const float4* W4 = (const float4*)W1;
    float4* Ws4 = (float4*)Ws;
    for (int i = tid; i < IN_DIM * HID / 4; i += 256) Ws4[i] = W4[i];
    int base = bid * 32;
    const float4* X4 = (const float4*)x;
    for (int i = tid; i < 32 * 32; i += 256) {           // 32 rows x 32 float4
        int ln = i >> 5, kq = i & 31;
        int node = base + ln;
        float4 v = (node < N_NODES) ? X4[(size_t)node * 32 + kq]
                                    : make_float4(0.f, 0.f, 0.f, 0.f);
        *(float4*)&xs[ln][kq * 4] = v;
    }
    __syncthreads();
    int np = tid >> 4;            // node pair 0..15
    int q  = tid & 15;            // col quad 0..15
    int n0 = np * 2, n1 = n0 + 1;
    float4 a0 = make_float4(0.f, 0.f, 0.f, 0.f);
    float4 a1 = a0;
    #pragma unroll 4
    for (int k4 = 0; k4 < IN_DIM; k4 += 4) {
        float4 xv0 = *(const float4*)&xs[n0][k4];
        float4 xv1 = *(const float4*)&xs[n1][k4];
        float4 w0 = Ws4[(k4 + 0) * 16 + q];
        float4 w1 = Ws4[(k4 + 1) * 16 + q];
        float4 w2 = Ws4[(k4 + 2) * 16 + q];
        float4 w3 = Ws4[(k4 + 3) * 16 + q];
        fma4(a0, xv0.x, w0); fma4(a0, xv0.y, w1); fma4(a0, xv0.z, w2); fma4(a0, xv0.w, w3);
        fma4(a1, xv1.x, w0); fma4(a1, xv1.y, w1); fma4(a1, xv1.z, w2); fma4(a1, xv1.w, w3);
    }
    int nd0 = base + n0, nd1 = base + n1;
    if (nd0 < N_NODES) {
        uint2 p = make_uint2(bf16pack2(a0.x, a0.y), bf16pack2(a0.z, a0.w));
        ((uint2*)h)[(size_t)nd0 * 16 + q] = p;
    }
    if (nd1 < N_NODES) {
        uint2 p = make_uint2(bf16pack2(a1.x, a1.y), bf16pack2(a1.z, a1.w));
        ((uint2*)h)[(size_t)nd1 * 16 + q] = p;
    }
}

// ---- 64-dim CSR gather over bf16 table, 4 record chains per wave ----
// Wave = one node. lane = grp*16 + l: grp = record chain 0..3, l = dim quad
// (dims 4l..4l+3 via uint2 T-row load: 16 lanes x 8B = 128B row).
// out[n] = dis[n]*(sum_e dis[s]*ew*T[s] + dis[n]*T[n]) (+bias,relu)
template <bool RELU_BIAS, bool OUT_BF16>
__global__ __launch_bounds__(256) void k_gather64(const uint2* __restrict__ rec,
                                                  const int* __restrict__ rs,
                                                  const float* __restrict__ dis,
                                                  const unsigned* __restrict__ T,
                                                  const float* __restrict__ bias,
                                                  void* __restrict__ outv) {
    int wave = (blockIdx.x * 256 + threadIdx.x) >> 6;
    if (wave >= N_NODES) return;
    int lane = threadIdx.x & 63;
    int grp  = lane >> 4;         // record chain 0..3
    int l    = lane & 15;         // dim quad within row
    int n = wave;
    int begin = ((n & 127) == 0) ? ((n >> 7) * BCAP) : rs[n - 1];
    int end = rs[n];
    const uint2* T2 = (const uint2*)T;

    float a0 = 0.f, a1 = 0.f, a2 = 0.f, a3 = 0.f;   // chain A accumulators
    float c0 = 0.f, c1 = 0.f, c2 = 0.f, c3 = 0.f;   // chain B accumulators
    int k = begin + grp;
    while (k + 4 < end) {                   // 2 records per group per iter (8/wave)
        uint2 r0 = rec[k];
        uint2 r1 = rec[k + 4];
        float d0 = dis[r0.x];
        float d1 = dis[r1.x];
        uint2 t0 = T2[(size_t)r0.x * 16 + l];
        uint2 t1 = T2[(size_t)r1.x * 16 + l];
        float n0 = d0 * __uint_as_float(r0.y);
        float n1 = d1 * __uint_as_float(r1.y);
        a0 += bflo(t0.x) * n0; a1 += bfhi(t0.x) * n0;
        a2 += bflo(t0.y) * n0; a3 += bfhi(t0.y) * n0;
        c0 += bflo(t1.x) * n1; c1 += bfhi(t1.x) * n1;
        c2 += bflo(t1.y) * n1; c3 += bfhi(t1.y) * n1;
        k += 8;
    }
    if (k < end) {                          // final record for this group
        uint2 r = rec[k];
        float d = dis[r.x];
        uint2 t = T2[(size_t)r.x * 16 + l];
        float nn = d * __uint_as_float(r.y);
        a0 += bflo(t.x) * nn; a1 += bfhi(t.x) * nn;
        a2 += bflo(t.y) * nn; a3 += bfhi(t.y) * nn;
    }
    a0 += c0; a1 += c1; a2 += c2; a3 += c3;
    // combine the 4 groups (butterfly over lane bits 4 and 5)
    a0 += __shfl_xor(a0, 16, 64); a1 += __shfl_xor(a1, 16, 64);
    a2 += __shfl_xor(a2, 16, 64); a3 += __shfl_xor(a3, 16, 64);
    a0 += __shfl_xor(a0, 32, 64); a1 += __shfl_xor(a1, 32, 64);
    a2 += __shfl_xor(a2, 32, 64); a3 += __shfl_xor(a3, 32, 64);
    if (grp == 0) {
        float di = dis[n];
        uint2 t = T2[(size_t)n * 16 + l];   // self-loop (pre-factored form)
        a0 += bflo(t.x) * di; a1 += bfhi(t.x) * di;
        a2 += bflo(t.y) * di; a3 += bfhi(t.y) * di;
        a0 *= di; a1 *= di; a2 *= di; a3 *= di;
        if (RELU_BIAS) {
            float4 b = ((const float4*)bias)[l];
            a0 = fmaxf(a0 + b.x, 0.f);
            a1 = fmaxf(a1 + b.y, 0.f);
            a2 = fmaxf(a2 + b.z, 0.f);
            a3 = fmaxf(a3 + b.w, 0.f);
        }
        if (OUT_BF16) {
            ((uint2*)outv)[(size_t)n * 16 + l] =
                make_uint2(bf16pack2(a0, a1), bf16pack2(a2, a3));
        } else {
            ((float4*)outv)[(size_t)n * 16 + l] = make_float4(a0, a1, a2, a3);
        }
    }
}

// ---- fused: h2 = relu(agg2 @ W2 + b2); pool[batch] += h2 (run-length) ----
__global__ __launch_bounds__(256) void k_gemm2_pool(const float* __restrict__ agg,
                                                    const float* __restrict__ W2,
                                                    const float* __restrict__ b2,
                                                    const int* __restrict__ batch,
                                                    float* __restrict__ pool) {
    __shared__ float Ws[HID * EMB];         // 32 KB
    __shared__ float as[NB2][HID];          // 16 KB (broadcast reads)
    __shared__ int   bs[NB2];
    int tid = threadIdx.x;
    const float4* W4 = (const float4*)W2;
    float4* Ws4 = (float4*)Ws;
    for (int i = tid; i < HID * EMB / 4; i += 256) Ws4[i] = W4[i];
    int base = blockIdx.x * NB2;
    const float4* A4 = (const float4*)agg;
    float4* as4 = (float4*)as;
    for (int i = tid; i < NB2 * HID / 4; i += 256) {
        int node = base + (i >> 4);
        as4[i] = (node < N_NODES) ? A4[(size_t)node * 16 + (i & 15)]
                                  : make_float4(0.f, 0.f, 0.f, 0.f);
    }
    if (tid < NB2) {
        int node = base + tid;
        bs[tid] = (node < N_NODES) ? batch[node] : -1;
    }
    __syncthreads();

    int c = tid & 31;             // column-quad id (4 cols)
    int s = tid >> 5;             // node slice 0..7 (8 contiguous nodes)
    int jc = c * 4;
    int nb = s * 8;
    float4 acc[8];
    #pragma unroll
    for (int i = 0; i < 8; ++i) acc[i] = make_float4(0.f, 0.f, 0.f, 0.f);
    #pragma unroll 4
    for (int k4 = 0; k4 < HID; k4 += 4) {
        float4 w0 = Ws4[(k4 + 0) * 32 + c];
        float4 w1 = Ws4[(k4 + 1) * 32 + c];
        float4 w2 = Ws4[(k4 + 2) * 32 + c];
        float4 w3 = Ws4[(k4 + 3) * 32 + c];
        #pragma unroll
        for (int i = 0; i < 8; ++i) {
            float4 av = *(const float4*)&as[nb + i][k4];
            fma4(acc[i], av.x, w0); fma4(acc[i], av.y, w1);
            fma4(acc[i], av.z, w2); fma4(acc[i], av.w, w3);
        }
    }
    // Epilogue: bias + relu + run-length pooled accumulate (batch sorted).
    float4 bq = *(const float4*)&b2[jc];
    float4 racc = make_float4(0.f, 0.f, 0.f, 0.f);
    int gcur = -1;
    #pragma unroll
    for (int i = 0; i < 8; ++i) {
        int g = bs[nb + i];
        if (g != gcur) {
            if (gcur >= 0) {
                float* p = &pool[(size_t)gcur * EMB + jc];
                atomicAdd(p + 0, racc.x); atomicAdd(p + 1, racc.y);
                atomicAdd(p + 2, racc.z); atomicAdd(p + 3, racc.w);
            }
            racc = make_float4(0.f, 0.f, 0.f, 0.f);
            gcur = g;
        }
        if (g < 0) continue;
        racc.x += fmaxf(acc[i].x + bq.x, 0.f);
        racc.y += fmaxf(acc[i].y + bq.y, 0.f);
        racc.z += fmaxf(acc[i].z + bq.z, 0.f);
        racc.w += fmaxf(acc[i].w + bq.w, 0.f);
    }
    if (gcur >= 0) {
        float* p = &pool[(size_t)gcur * EMB + jc];
        atomicAdd(p + 0, racc.x); atomicAdd(p + 1, racc.y);
        atomicAdd(p + 2, racc.z); atomicAdd(p + 3, racc.w);
    }
}

__global__ void k_divide(const float* __restrict__ pool, const int* __restrict__ gstart,
                         float* __restrict__ out) {
    int idx = blockIdx.x * blockDim.x + threadIdx.x;
    if (idx >= N_GRAPHS * EMB) return;
    int g = idx >> 7;
    float c = (float)(gstart[g + 1] - gstart[g]);
    out[idx] = pool[idx] / fmaxf(c, 1.0f);
}

extern "C" void kernel_launch(void* const* d_in, const int* in_sizes, int n_in,
                              void* d_out, int out_size, void* d_ws, size_t ws_size,
                              hipStream_t stream) {
    const float* x     = (const float*)d_in[0];
    const int*   eidx  = (const int*)d_in[1];     // [2, E]: src then dst
    const float* ew    = (const float*)d_in[2];
    const int*   batch = (const int*)d_in[3];
    const float* W1    = (const float*)d_in[4];
    const float* b1    = (const float*)d_in[5];
    const float* W2    = (const float*)d_in[6];
    const float* b2    = (const float*)d_in[7];
    float* out = (float*)d_out;

    const int* src = eidx;
    const int* dst = eidx + N_EDGES;

    float* ws     = (float*)d_ws;
    float* pool   = ws + OFF_POOL;
    int*   gcur   = (int*)(ws + OFF_GCUR);
    int*   gstart = (int*)(ws + OFF_GST);
    float* dis    = ws + OFF_DIS;
    int*   rs     = (int*)(ws + OFF_RS);
    uint2* rec    = (uint2*)(ws + OFF_REC);
    uint4* part   = (uint4*)(ws + OFF_PART);
    unsigned* h1  = (unsigned*)(ws + OFF_H1);   // bf16x2; overlays part (dead after P3)
    unsigned* h1p = (unsigned*)(ws + OFF_H1P);  // bf16x2
    float* agg2   = ws + OFF_AGG2;              // f32; overlays h1p (dead after gather1)

    // Zero pool + bucket cursors in one memset (they are adjacent).
    (void)hipMemsetAsync(pool, 0, (size_t)(32768 + NBKT) * sizeof(float), stream);

    // Edges -> bucket segments (atomic range claims) + gstart detection.
    k_p2<<<EB + GSB, 256, 0, stream>>>(src, dst, ew, gcur, part, batch, gstart);

    // Per-bucket CSR finalize + degree/dis, het-fused with layer-1 linear.
    k_p3_gemm1<<<NBKT + GB, 256, 0, stream>>>(part, gcur, rs, dis, rec, x, W1, h1p);

    // Layer 1 aggregate + bias + relu: bf16 table -> bf16 h1.
    k_gather64<true, true><<<N_NODES / 4, 256, 0, stream>>>(rec, rs, dis, h1p, b1, h1);

    // Layer 2 aggregate BEFORE the linear: bf16 h1 -> f32 agg2.
    k_gather64<false, false><<<N_NODES / 4, 256, 0, stream>>>(rec, rs, dis, h1, nullptr, agg2);

    // Fused layer-2 linear + relu + run-length pooled accumulate.
    k_gemm2_pool<<<(N_NODES + NB2 - 1) / NB2, 256, 0, stream>>>(agg2, W2, b2, batch, pool);

    k_divide<<<(N_GRAPHS * EMB + 255) / 256, 256, 0, stream>>>(pool, gstart, out);
}